// Round 1
// baseline (304.024 us; speedup 1.0000x reference)
//
#include <hip/hip_runtime.h>

// YOLO layer: (64, 255, 52, 52) f32 -> (64, 8112, 85) f32
// out[b][a*2704+gy*52+gx][e] = f_e(x[b][a*85+e][gy][gx])
//   e==0: (sigmoid(v)+gx)*8 ; e==1: (sigmoid(v)+gy)*8
//   e==2: exp(v)*anchors[a][0] ; e==3: exp(v)*anchors[a][1]  (anchor/stride*stride)
//   else: sigmoid(v)

#define NBATCH 64
#define NANCH  3
#define NCLS   80
#define NGRID  52
#define NELEM  85                 // 5 + NCLS
#define GY     2                  // gy rows per workgroup
#define SP     (GY * NGRID)       // 104 spatial elements per block
#define F4E    (SP / 4)           // 26 float4 per e-row
#define NF4    (NELEM * F4E)      // 2210 float4 per block (= 8840 floats)
#define STRIDE_F 8.0f             // 416 / 52

__device__ __forceinline__ float fast_sigmoid(float v) {
    return __builtin_amdgcn_rcpf(1.0f + __expf(-v));
}

__global__ __launch_bounds__(256) void yolo_kernel(
    const float* __restrict__ x,
    const float* __restrict__ anchors,
    float* __restrict__ out)
{
    // LDS buffer holds the block's output chunk in EXACT output layout:
    // lds[s*85 + e], s in [0,104). 8840 floats = 35,360 B -> 4 blocks/CU.
    __shared__ float4 lds4[NF4];
    float* lds = reinterpret_cast<float*>(lds4);

    const int blk = blockIdx.x;                  // 0 .. 4991
    const int gyb = blk % (NGRID / GY);          // 0 .. 25
    const int a   = (blk / (NGRID / GY)) % NANCH;
    const int b   = blk / ((NGRID / GY) * NANCH);
    const int gy0 = gyb * GY;

    const float aw = anchors[a * 2 + 0];
    const float ah = anchors[a * 2 + 1];

    const int t = threadIdx.x;

    // Input base: x[b][a*85 + 0][gy0][0]; e-rows stride NGRID*NGRID floats.
    const float4* __restrict__ xin = reinterpret_cast<const float4*>(
        x + ((size_t)(b * NANCH + a) * NELEM) * (NGRID * NGRID) + (size_t)gy0 * NGRID);

    // ---- Phase 1: coalesced float4 loads, transform, transpose-scatter to LDS ----
    for (int F = t; F < NF4; F += 256) {
        const int e = F / F4E;
        const int q = F - e * F4E;               // float4 index within e-row
        const float4 v = xin[(size_t)e * (NGRID * NGRID / 4) + q];
        const int s0 = q * 4;                    // spatial index of v.x
        float r[4] = {v.x, v.y, v.z, v.w};
        #pragma unroll
        for (int k = 0; k < 4; ++k) {
            const int s = s0 + k;
            const float vv = r[k];
            float o;
            if (e == 0) {
                const int gx = s % NGRID;
                o = (fast_sigmoid(vv) + (float)gx) * STRIDE_F;
            } else if (e == 1) {
                const int gy = gy0 + s / NGRID;
                o = (fast_sigmoid(vv) + (float)gy) * STRIDE_F;
            } else if (e == 2) {
                o = __expf(vv) * aw;
            } else if (e == 3) {
                o = __expf(vv) * ah;
            } else {
                o = fast_sigmoid(vv);
            }
            lds[s * NELEM + e] = o;
        }
    }

    __syncthreads();

    // ---- Phase 2: pure aligned float4 copy LDS -> global (fully coalesced) ----
    // Output chunk base: out[b][a*2704 + gy0*52][0], contiguous 8840 floats.
    float4* __restrict__ op = reinterpret_cast<float4*>(
        out + ((size_t)b * NANCH * NGRID * NGRID +
               (size_t)a * NGRID * NGRID +
               (size_t)gy0 * NGRID) * NELEM);
    for (int F = t; F < NF4; F += 256) {
        op[F] = lds4[F];
    }
}

extern "C" void kernel_launch(void* const* d_in, const int* in_sizes, int n_in,
                              void* d_out, int out_size, void* d_ws, size_t ws_size,
                              hipStream_t stream) {
    const float* x       = (const float*)d_in[0];
    const float* anchors = (const float*)d_in[1];
    float* out           = (float*)d_out;

    const int nblocks = NBATCH * NANCH * (NGRID / GY);   // 4992
    yolo_kernel<<<nblocks, 256, 0, stream>>>(x, anchors, out);
}

// Round 4
// 301.474 us; speedup vs baseline: 1.0085x; 1.0085x over previous
//
#include <hip/hip_runtime.h>

// YOLO layer: (64, 255, 52, 52) f32 -> (64, 8112, 85) f32
// out[b][a*2704+gy*52+gx][e] = f_e(x[b][a*85+e][gy][gx])
//   e==0: (sigmoid(v)+gx)*8 ; e==1: (sigmoid(v)+gy)*8
//   e==2: exp(v)*anchors[a][0] ; e==3: exp(v)*anchors[a][1]
//   else: sigmoid(v)
//
// NOTE: no nontemporal stores — nt bypasses L2 and races the harness's
// L2-cached poison/readback (post-timing divergence in round 3).

#define NBATCH 64
#define NANCH  3
#define NGRID  52
#define NELEM  85                 // 5 + 80 classes
#define GY     2                  // gy rows per workgroup
#define SP     (GY * NGRID)       // 104 spatial elements per block
#define F4E    (SP / 4)           // 26 float4 per e-row
#define NF4    (NELEM * F4E)      // 2210 float4 per block (= 8840 floats)
#define NT     512                // threads per block (8 waves)
#define NITER  5                  // ceil(2210 / 512)
#define STRIDE_F 8.0f             // 416 / 52

typedef float vfloat4 __attribute__((ext_vector_type(4)));

__device__ __forceinline__ float fast_sigmoid(float v) {
    return __builtin_amdgcn_rcpf(1.0f + __expf(-v));
}

__global__ __launch_bounds__(NT, 6) void yolo_kernel(
    const float* __restrict__ x,
    const float* __restrict__ anchors,
    float* __restrict__ out)
{
    // LDS holds the block's output chunk in EXACT output layout:
    // lds[s*85 + e], s in [0,104). 8840 floats = 35,360 B -> 4 blocks/CU,
    // 4 x 8 waves = 32 waves/CU (full occupancy).
    __shared__ vfloat4 lds4[NF4];
    float* lds = reinterpret_cast<float*>(lds4);

    const int blk = blockIdx.x;                  // 0 .. 4991
    const int gyb = blk % (NGRID / GY);          // 0 .. 25
    const int a   = (blk / (NGRID / GY)) % NANCH;
    const int b   = blk / ((NGRID / GY) * NANCH);
    const int gy0 = gyb * GY;

    const float aw = anchors[a * 2 + 0];
    const float ah = anchors[a * 2 + 1];

    const int t = threadIdx.x;

    // Input base: x[b][a*85 + 0][gy0][0]; e-rows stride 2704 floats.
    const vfloat4* __restrict__ xin = reinterpret_cast<const vfloat4*>(
        x + (size_t)(b * NANCH + a) * (NELEM * NGRID * NGRID) + (size_t)gy0 * NGRID);

    // ---- Phase 1: batched coalesced float4 loads, transform, transpose to LDS ----
    // Fixed trip count + full unroll lets the compiler issue all 5 loads
    // before the first use (one vmcnt batch instead of 5 serialized waits).
    #pragma unroll
    for (int i = 0; i < NITER; ++i) {
        const int F = t + i * NT;
        if (F < NF4) {
            const int e = F / F4E;               // magic-mul div by 26
            const int q = F - e * F4E;           // float4 index within e-row
            const vfloat4 v = xin[(size_t)e * (NGRID * NGRID / 4) + q];
            const int s0 = q * 4;                // spatial index of v.x
            #pragma unroll
            for (int k = 0; k < 4; ++k) {
                const int s = s0 + k;
                const float vv = v[k];
                float o;
                if (e >= 4) {                    // common case first (81/85 rows)
                    o = fast_sigmoid(vv);
                } else if (e == 0) {
                    o = (fast_sigmoid(vv) + (float)(s % NGRID)) * STRIDE_F;
                } else if (e == 1) {
                    o = (fast_sigmoid(vv) + (float)(gy0 + s / NGRID)) * STRIDE_F;
                } else if (e == 2) {
                    o = __expf(vv) * aw;
                } else {
                    o = __expf(vv) * ah;
                }
                lds[s * NELEM + e] = o;
            }
        }
    }

    __syncthreads();

    // ---- Phase 2: aligned float4 copy LDS -> global (fully coalesced) ----
    vfloat4* __restrict__ op = reinterpret_cast<vfloat4*>(
        out + ((size_t)(b * NANCH + a) * (NGRID * NGRID) + (size_t)gy0 * NGRID) * NELEM);
    #pragma unroll
    for (int i = 0; i < NITER; ++i) {
        const int F = t + i * NT;
        if (F < NF4) {
            op[F] = lds4[F];
        }
    }
}

extern "C" void kernel_launch(void* const* d_in, const int* in_sizes, int n_in,
                              void* d_out, int out_size, void* d_ws, size_t ws_size,
                              hipStream_t stream) {
    const float* x       = (const float*)d_in[0];
    const float* anchors = (const float*)d_in[1];
    float* out           = (float*)d_out;

    const int nblocks = NBATCH * NANCH * (NGRID / GY);   // 4992
    yolo_kernel<<<nblocks, NT, 0, stream>>>(x, anchors, out);
}